// Round 1
// baseline (1324.102 us; speedup 1.0000x reference)
//
#include <hip/hip_runtime.h>
#include <math.h>

#define F 64
#define WPB 4    // waves per block
#define RPW 16   // rows per wave in fused kernels

// ---------- CSR build ----------

__global__ __launch_bounds__(256) void deg_kernel(const int* __restrict__ ei, int E,
                                                  int* __restrict__ deg) {
    int e = blockIdx.x * 256 + threadIdx.x;
    if (e >= E) return;
    int r = ei[e], c = ei[E + e];
    if (r != c) atomicAdd(&deg[r], 1);
}

__global__ __launch_bounds__(256) void scan1_kernel(const int* __restrict__ deg,
                                                    int* __restrict__ rp,
                                                    int* __restrict__ bsum, int Nv) {
    __shared__ int sh[256];
    int t = threadIdx.x;
    int base = blockIdx.x * 1024 + t * 4;
    int v0 = (base + 0 < Nv) ? deg[base + 0] : 0;
    int v1 = (base + 1 < Nv) ? deg[base + 1] : 0;
    int v2 = (base + 2 < Nv) ? deg[base + 2] : 0;
    int v3 = (base + 3 < Nv) ? deg[base + 3] : 0;
    int s = v0 + v1 + v2 + v3;
    sh[t] = s;
    __syncthreads();
    for (int off = 1; off < 256; off <<= 1) {
        int a = (t >= off) ? sh[t - off] : 0;
        __syncthreads();
        sh[t] += a;
        __syncthreads();
    }
    int run = sh[t] - s;  // exclusive prefix for this thread
    run += v0; if (base + 0 < Nv) rp[base + 1] = run;
    run += v1; if (base + 1 < Nv) rp[base + 2] = run;
    run += v2; if (base + 2 < Nv) rp[base + 3] = run;
    run += v3; if (base + 3 < Nv) rp[base + 4] = run;
    if (t == 255) bsum[blockIdx.x] = sh[255];
}

__global__ __launch_bounds__(256) void scan2_kernel(int* __restrict__ bsum, int nb) {
    __shared__ int sh[256];
    int t = threadIdx.x;
    int v = (t < nb) ? bsum[t] : 0;
    sh[t] = v;
    __syncthreads();
    for (int off = 1; off < 256; off <<= 1) {
        int a = (t >= off) ? sh[t - off] : 0;
        __syncthreads();
        sh[t] += a;
        __syncthreads();
    }
    if (t < nb) bsum[t] = sh[t] - v;  // exclusive
}

__global__ __launch_bounds__(256) void scan3_kernel(int* __restrict__ rp,
                                                    const int* __restrict__ bsum, int Nv) {
    int i = blockIdx.x * 256 + threadIdx.x;
    if (i == 0) rp[0] = 0;
    if (i < Nv) rp[i + 1] += bsum[i >> 10];
}

__global__ __launch_bounds__(256) void dinv_kernel(const int* __restrict__ deg,
                                                   float* __restrict__ dinv, int Nv) {
    int i = blockIdx.x * 256 + threadIdx.x;
    if (i >= Nv) return;
    int d = deg[i];
    dinv[i] = d > 0 ? rsqrtf((float)d) : 0.f;
}

__global__ __launch_bounds__(256) void scatter_kernel(const int* __restrict__ ei, int E,
                                                      const int* __restrict__ rp,
                                                      int* __restrict__ fill,
                                                      const float* __restrict__ dinv,
                                                      int2* __restrict__ ce) {
    int e = blockIdx.x * 256 + threadIdx.x;
    if (e >= E) return;
    int r = ei[e], c = ei[E + e];
    if (r == c) return;
    int slot = rp[r] + atomicAdd(&fill[r], 1);
    float w = -dinv[r] * dinv[c];
    ce[slot] = make_int2(c, __float_as_int(w));
}

// ---------- acc = x @ W0 (init) ----------

__global__ __launch_bounds__(256, 4) void mm_init_kernel(const float* __restrict__ X,
                                                         const float* __restrict__ W0,
                                                         float* __restrict__ acc, int Nv) {
    __shared__ float sh[WPB][F];
    int wave = threadIdx.x >> 6, lane = threadIdx.x & 63;
    float wr[F];
#pragma unroll
    for (int j = 0; j < F; j++) wr[j] = W0[j * F + lane];  // column `lane` of W0
    for (int r = 0; r < RPW; r++) {
        int i = blockIdx.x * (WPB * RPW) + r * WPB + wave;
        bool act = i < Nv;
        int ii = act ? i : 0;
        float xv = X[(size_t)ii * F + lane];
        sh[wave][lane] = xv;
        __syncthreads();
        float a = 0.f;
        const float4* tb = (const float4*)sh[wave];
#pragma unroll
        for (int j4 = 0; j4 < F / 4; j4++) {
            float4 tv = tb[j4];
            a = fmaf(tv.x, wr[4 * j4 + 0], a);
            a = fmaf(tv.y, wr[4 * j4 + 1], a);
            a = fmaf(tv.z, wr[4 * j4 + 2], a);
            a = fmaf(tv.w, wr[4 * j4 + 3], a);
        }
        if (act) acc[(size_t)i * F + lane] = a;
        __syncthreads();
    }
}

// ---------- fused prop (SpMV) + recurrence + acc += tk @ Wk ----------

__global__ __launch_bounds__(256, 4) void prop_mm_kernel(const float* __restrict__ Tm1,
                                                         const float* __restrict__ Tm2,
                                                         float* __restrict__ Tout,
                                                         const int* __restrict__ rp,
                                                         const int2* __restrict__ ce,
                                                         const float* __restrict__ Wk,
                                                         float* __restrict__ acc,
                                                         int Nv, int first) {
    __shared__ float sh[WPB][F];
    int wave = threadIdx.x >> 6, lane = threadIdx.x & 63;
    float wr[F];
#pragma unroll
    for (int j = 0; j < F; j++) wr[j] = Wk[j * F + lane];  // column `lane` of Wk
    for (int r = 0; r < RPW; r++) {
        int i = blockIdx.x * (WPB * RPW) + r * WPB + wave;
        bool act = i < Nv;
        int ii = act ? i : 0;
        int s = rp[ii], e = rp[ii + 1];
        float s0 = 0.f, s1 = 0.f, s2 = 0.f, s3 = 0.f;
        int p = s;
        for (; p + 4 <= e; p += 4) {  // 4-wide to break the load-fma latency chain
            int2 a = ce[p], b = ce[p + 1], c2 = ce[p + 2], d = ce[p + 3];
            s0 = fmaf(__int_as_float(a.y),  Tm1[(size_t)a.x  * F + lane], s0);
            s1 = fmaf(__int_as_float(b.y),  Tm1[(size_t)b.x  * F + lane], s1);
            s2 = fmaf(__int_as_float(c2.y), Tm1[(size_t)c2.x * F + lane], s2);
            s3 = fmaf(__int_as_float(d.y),  Tm1[(size_t)d.x  * F + lane], s3);
        }
        for (; p < e; p++) {
            int2 a = ce[p];
            s0 = fmaf(__int_as_float(a.y), Tm1[(size_t)a.x * F + lane], s0);
        }
        float sum = (s0 + s1) + (s2 + s3);
        // recurrence: tk = 2*prop - tkm2 ; for k==1 tk = prop(x)
        float tk = first ? sum : fmaf(2.f, sum, -Tm2[(size_t)ii * F + lane]);
        sh[wave][lane] = tk;
        __syncthreads();
        float a2 = 0.f;
        const float4* tb = (const float4*)sh[wave];
#pragma unroll
        for (int j4 = 0; j4 < F / 4; j4++) {
            float4 tv = tb[j4];
            a2 = fmaf(tv.x, wr[4 * j4 + 0], a2);
            a2 = fmaf(tv.y, wr[4 * j4 + 1], a2);
            a2 = fmaf(tv.z, wr[4 * j4 + 2], a2);
            a2 = fmaf(tv.w, wr[4 * j4 + 3], a2);
        }
        if (act) {
            Tout[(size_t)i * F + lane] = tk;   // may equal Tm2 buffer: same-thread RAW, safe
            acc[(size_t)i * F + lane] += a2;
        }
        __syncthreads();
    }
}

// ---------- bias + LayerNorm + ELU (in place on d_out) ----------

__global__ __launch_bounds__(256) void ln_elu_kernel(float* __restrict__ io,
                                                     const float* __restrict__ bias,
                                                     const float* __restrict__ lnw,
                                                     const float* __restrict__ lnb, int Nv) {
    int wave = threadIdx.x >> 6, lane = threadIdx.x & 63;
    int i = blockIdx.x * WPB + wave;
    if (i >= Nv) return;
    float v = io[(size_t)i * F + lane] + bias[lane];
    float s = v;
#pragma unroll
    for (int off = 1; off < 64; off <<= 1) s += __shfl_xor(s, off, 64);
    float mu = s * (1.f / F);
    float d = v - mu;
    float q = d * d;
#pragma unroll
    for (int off = 1; off < 64; off <<= 1) q += __shfl_xor(q, off, 64);
    float y = d * rsqrtf(q * (1.f / F) + 1e-5f) * lnw[lane] + lnb[lane];
    io[(size_t)i * F + lane] = y > 0.f ? y : expm1f(y);
}

// ---------- host ----------

extern "C" void kernel_launch(void* const* d_in, const int* in_sizes, int n_in,
                              void* d_out, int out_size, void* d_ws, size_t ws_size,
                              hipStream_t stream) {
    (void)n_in; (void)out_size;
    const float* x    = (const float*)d_in[0];
    const int*   ei   = (const int*)d_in[1];
    const float* W    = (const float*)d_in[2];
    const float* bias = (const float*)d_in[3];
    const float* lnw  = (const float*)d_in[4];
    const float* lnb  = (const float*)d_in[5];
    float* out = (float*)d_out;

    int Nv = in_sizes[0] / F;
    int E  = in_sizes[1] / 2;
    int K  = in_sizes[2] / (F * F);

    char* base = (char*)d_ws;
    size_t off = 0;
    auto alloc = [&](size_t b) -> void* {
        void* p = base + off;
        off += (b + 255) & ~(size_t)255;
        return p;
    };
    int*   deg  = (int*)alloc((size_t)Nv * 4);
    int*   fill = (int*)alloc((size_t)Nv * 4);
    int*   rp   = (int*)alloc(((size_t)Nv + 1) * 4);
    int    nb   = (Nv + 1023) / 1024;
    int*   bsum = (int*)alloc((size_t)nb * 4);
    float* dinv = (float*)alloc((size_t)Nv * 4);
    int2*  ce   = (int2*)alloc((size_t)E * 8);
    float* Ta   = (float*)alloc((size_t)Nv * F * 4);
    float* Tb   = (float*)alloc((size_t)Nv * F * 4);
    if (off > ws_size) return;  // ~66 MB required

    hipMemsetAsync(deg, 0, (size_t)Nv * 4, stream);
    hipMemsetAsync(fill, 0, (size_t)Nv * 4, stream);

    int gE = (E + 255) / 256, gN = (Nv + 255) / 256;
    deg_kernel<<<gE, 256, 0, stream>>>(ei, E, deg);
    scan1_kernel<<<nb, 256, 0, stream>>>(deg, rp, bsum, Nv);
    scan2_kernel<<<1, 256, 0, stream>>>(bsum, nb);
    scan3_kernel<<<gN, 256, 0, stream>>>(rp, bsum, Nv);
    dinv_kernel<<<gN, 256, 0, stream>>>(deg, dinv, Nv);
    scatter_kernel<<<gE, 256, 0, stream>>>(ei, E, rp, fill, dinv, ce);

    int rowsPerBlock = WPB * RPW;
    int gR = (Nv + rowsPerBlock - 1) / rowsPerBlock;
    mm_init_kernel<<<gR, 256, 0, stream>>>(x, W, out, Nv);

    const float* tm1 = x;
    const float* tm2 = nullptr;
    for (int k = 1; k < K; k++) {
        float* to = (k & 1) ? Ta : Tb;
        prop_mm_kernel<<<gR, 256, 0, stream>>>(tm1, tm2, to, rp, ce,
                                               W + (size_t)k * F * F, out, Nv, k == 1 ? 1 : 0);
        tm2 = (k == 1) ? x : tm1;
        tm1 = to;
    }

    ln_elu_kernel<<<(Nv + WPB - 1) / WPB, 256, 0, stream>>>(out, bias, lnw, lnb, Nv);
}